// Round 6
// baseline (376.576 us; speedup 1.0000x reference)
//
#include <hip/hip_runtime.h>
#include <stdint.h>

#define B_ 8
#define C_ 256
#define N_ 4096

typedef __attribute__((ext_vector_type(8))) short short8;
typedef __attribute__((ext_vector_type(4))) float float4v;
typedef __attribute__((ext_vector_type(16))) float floatx16;

__device__ __forceinline__ uint16_t f2bfr(float f) {
  return (uint16_t)((__float_as_uint(f) + 0x8000u) >> 16);
}
__device__ __forceinline__ uint32_t pkbf(float lo, float hi) {
  return ((__float_as_uint(hi) + 0x8000u) & 0xffff0000u) |
         ((__float_as_uint(lo) + 0x8000u) >> 16);
}
// 16B LDS read from an 8B-aligned address as 2x b64 (rows are 152B-strided,
// so b128 alignment is unavailable; b64 keeps the 16-bank spread of s=38dw)
__device__ __forceinline__ short8 ld8(const uint16_t* p) {
  union { ushort4 h[2]; short8 v; } u;
  u.h[0] = *reinterpret_cast<const ushort4*>(p);
  u.h[1] = *reinterpret_cast<const ushort4*>(p + 4);
  return u.v;
}

// ---------------------------------------------------------------------------
// Kernel 0: W fp32 -> Wc bf16, biases fp32.
// ---------------------------------------------------------------------------
__global__ __launch_bounds__(256) void wconv_kernel(
    const float* __restrict__ Wq, const float* __restrict__ bq,
    const float* __restrict__ Wk, const float* __restrict__ bk,
    const float* __restrict__ Wv, const float* __restrict__ bv,
    uint16_t* __restrict__ Wc, float* __restrict__ bc)
{
  int tg = blockIdx.x * 256 + threadIdx.x;
  int idx = tg * 4;
  const float* src = (idx < 8192) ? (Wq + idx)
                   : (idx < 16384) ? (Wk + (idx - 8192))
                                   : (Wv + (idx - 16384));
  float4 wv = *reinterpret_cast<const float4*>(src);
  uint2 o;
  o.x = pkbf(wv.x, wv.y);
  o.y = pkbf(wv.z, wv.w);
  *reinterpret_cast<uint2*>(Wc + idx) = o;
  if (tg < 320) bc[tg] = (tg < 32) ? bq[tg] : (tg < 64) ? bk[tg - 32] : bv[tg - 64];
}

// ---------------------------------------------------------------------------
// Kernel 1: QKV via MFMA. 512 thr, grid (N/64,B). k-split halves keep live
// VGPRs ~115 (< the 128 cap of bounds(512,4)): bx half = 32 regs. xs rows
// 268 u16 (536B, 8B-aligned; s=134dw == 6 mod 32 -> b64 reads 4-way max).
// ---------------------------------------------------------------------------
__global__ __launch_bounds__(512, 4) void qkv_mfma(
    const float* __restrict__ x, const uint16_t* __restrict__ Wc,
    const float* __restrict__ bc,
    uint16_t* __restrict__ Qw, uint16_t* __restrict__ Kw, uint16_t* __restrict__ Vw)
{
  __shared__ __align__(16) uint16_t xs[64][268];
  const int b = blockIdx.y, n0 = blockIdx.x * 64;
  const int tid = threadIdx.x;
  const int nl = tid & 63, grp = tid >> 6;
  const int w = grp, l15 = tid & 15, q = (tid & 63) >> 4;
  const int nb = w & 3;

  const float* xb = x + (size_t)b * C_ * N_ + n0;
  #pragma unroll
  for (int it = 0; it < 16; ++it) {
    int c2 = it * 16 + grp * 2;
    float f0 = xb[(size_t)c2 * N_ + nl];
    float f1 = xb[(size_t)(c2 + 1) * N_ + nl];
    *reinterpret_cast<uint32_t*>(&xs[nl][c2]) = pkbf(f0, f1);
  }
  __syncthreads();

  float4v acc[10];
  #pragma unroll
  for (int i = 0; i < 10; ++i) acc[i] = (float4v){0.f, 0.f, 0.f, 0.f};

  const int ob0 = (w >> 2) * 10;
  #pragma unroll
  for (int h2 = 0; h2 < 2; ++h2) {
    short8 bx[4];
    #pragma unroll
    for (int kb = 0; kb < 4; ++kb)
      bx[kb] = ld8(&xs[nb * 16 + l15][h2 * 128 + kb * 32 + q * 8]);
    #pragma unroll
    for (int oi = 0; oi < 10; ++oi) {
      int ob = ob0 + oi;
      const uint16_t* wr = Wc + (size_t)(ob * 16 + l15) * 256 + h2 * 128 + q * 8;
      short8 aw[4];
      #pragma unroll
      for (int kb = 0; kb < 4; ++kb)
        aw[kb] = *reinterpret_cast<const short8*>(wr + kb * 32);
      #pragma unroll
      for (int kb = 0; kb < 4; ++kb)
        acc[oi] = __builtin_amdgcn_mfma_f32_16x16x32_bf16(aw[kb], bx[kb], acc[oi], 0, 0, 0);
    }
  }

  // ---- Q/K epilogue (ob 0..3 live in waves 0-3) via LDS transpose ----
  __syncthreads();
  uint16_t (*qs)[72] = reinterpret_cast<uint16_t(*)[72]>(&xs[0][0]);
  if (w < 4) {
    #pragma unroll
    for (int oi = 0; oi < 4; ++oi) {
      float4v a = acc[oi];
      const float* bb = bc + oi * 16 + q * 4;
      uint2 pk2;
      pk2.x = pkbf(a.x + bb[0], a.y + bb[1]);
      pk2.y = pkbf(a.z + bb[2], a.w + bb[3]);
      *reinterpret_cast<uint2*>(&qs[nb * 16 + l15][oi * 16 + q * 4]) = pk2;
    }
  }
  __syncthreads();
  if (tid < 256) {
    int n = tid >> 2, sub = tid & 3;
    const uint16_t* row = qs[n];
    uint4 d0 = *reinterpret_cast<const uint4*>(&row[sub * 16]);
    uint4 d1 = *reinterpret_cast<const uint4*>(&row[sub * 16 + 8]);
    size_t nn = (size_t)b * N_ + n0 + n;
    if (sub < 2) {
      uint4* dst = reinterpret_cast<uint4*>(Qw + nn * 32 + sub * 16);
      dst[0] = d0; dst[1] = d1;
    } else {
      uint4* dst = reinterpret_cast<uint4*>(Kw + nn * 32 + (sub - 2) * 16);
      dst[0] = d0; dst[1] = d1;
    }
  }
  // ---- V epilogue: ob in [4,20) -> c = ob*16-64, layout [B][C][N] ----
  #pragma unroll
  for (int oi = 0; oi < 10; ++oi) {
    int ob = ob0 + oi;
    if (ob < 4) continue;
    float4v a = acc[oi];
    const float* bb = bc + ob * 16 + q * 4;
    int c = ob * 16 - 64 + q * 4;
    size_t base = ((size_t)b * C_ + c) * N_ + n0 + nb * 16 + l15;
    Vw[base         ] = f2bfr(a.x + bb[0]);
    Vw[base +   N_  ] = f2bfr(a.y + bb[1]);
    Vw[base + 2 * N_] = f2bfr(a.z + bb[2]);
    Vw[base + 3 * N_] = f2bfr(a.w + bb[3]);
  }
}

// ---------------------------------------------------------------------------
// Kernel 2: MFMA flash attention, skewed pipeline. 512 thr, grid (N/64,B).
// Iter t: global V[t] + K[t+2] loads issue first; S[t+1] (16x16 MFMA -> exp
// -> P LDS write, buf (t+1)&1); PV[t] (32x32x16 MFMA, A = P buf t&1, B = V
// regs); ONE barrier. P write/read are separated by a full iteration, so the
// barrier carries no intra-iteration dependency. Ks/Ps rows 152B (38 dw == 6
// mod 32 -> b64 accesses max 4-way banks vs r5's 8-way). Wave w: S rows
// mbp=(w>>2)*2+{0,1}, nb=w&3; PV m-half w&1, c = (w>>1)*64+{0,32}.
// Epilogue: D (32x32 layout) -> LDS transpose (overlaid) -> coalesced float4.
// ---------------------------------------------------------------------------
__global__ __launch_bounds__(512, 4) void attn_mfma(
    const uint16_t* __restrict__ Qw, const uint16_t* __restrict__ Kw,
    const uint16_t* __restrict__ Vw, const float* __restrict__ x,
    const float* __restrict__ gamma, float* __restrict__ out)
{
  __shared__ __align__(16) union Smem {
    struct { uint16_t Ks[2][64 * 76]; uint16_t Ps[2][64 * 76]; } m;  // 38912B
    float Os[128 * 68];                                              // 34816B
  } sm;
  __shared__ float Ls[64];

  const int b = blockIdx.y, m0 = blockIdx.x * 64;
  const int tid = threadIdx.x;
  const int w = tid >> 6, lane = tid & 63;
  const int l15 = lane & 15, q = lane >> 4;
  const int l31 = lane & 31, half = lane >> 5;
  const int nb = w & 3, mbp = (w >> 2) * 2;     // S assignment
  const int mh = w & 1, cq = w >> 1;            // PV assignment
  const int kr = tid >> 3, kc = tid & 7;        // K staging map

  const uint16_t* Kb = Kw + (size_t)b * N_ * 32;
  const short8 qf0 = *reinterpret_cast<const short8*>(
      Qw + ((size_t)b * N_ + m0 + (mbp    ) * 16 + l15) * 32 + q * 8);
  const short8 qf1 = *reinterpret_cast<const short8*>(
      Qw + ((size_t)b * N_ + m0 + (mbp + 1) * 16 + l15) * 32 + q * 8);
  const uint16_t* Vbase = Vw + ((size_t)b * C_ + cq * 64 + l31) * (size_t)N_;

  floatx16 O[2];
  #pragma unroll
  for (int i = 0; i < 16; ++i) { O[0][i] = 0.f; O[1][i] = 0.f; }
  float rs0 = 0.f, rs1 = 0.f;
  const float4v zero4 = (float4v){0.f, 0.f, 0.f, 0.f};

  // ---- prolog: stage K0; S[0] -> Ps[0]; stage K1 ----
  {
    ushort4 k0 = *reinterpret_cast<const ushort4*>(Kb + (size_t)kr * 32 + kc * 4);
    *reinterpret_cast<ushort4*>(&sm.m.Ks[0][kr * 76 + kc * 4]) = k0;
    if (tid < 64) Ls[tid] = 0.f;
  }
  __syncthreads();
  {
    ushort4 k1 = *reinterpret_cast<const ushort4*>(Kb + (size_t)(64 + kr) * 32 + kc * 4);
    short8 kf = ld8(&sm.m.Ks[0][(nb * 16 + l15) * 76 + q * 8]);
    float4v s0 = __builtin_amdgcn_mfma_f32_16x16x32_bf16(kf, qf0, zero4, 0, 0, 0);
    float4v s1 = __builtin_amdgcn_mfma_f32_16x16x32_bf16(kf, qf1, zero4, 0, 0, 0);
    {
      float p0 = __expf(s0.x), p1 = __expf(s0.y), p2 = __expf(s0.z), p3 = __expf(s0.w);
      rs0 += (p0 + p1) + (p2 + p3);
      uint2 pw; pw.x = pkbf(p0, p1); pw.y = pkbf(p2, p3);
      *reinterpret_cast<uint2*>(&sm.m.Ps[0][((mbp)*16 + l15) * 76 + nb * 16 + q * 4]) = pw;
    }
    {
      float p0 = __expf(s1.x), p1 = __expf(s1.y), p2 = __expf(s1.z), p3 = __expf(s1.w);
      rs1 += (p0 + p1) + (p2 + p3);
      uint2 pw; pw.x = pkbf(p0, p1); pw.y = pkbf(p2, p3);
      *reinterpret_cast<uint2*>(&sm.m.Ps[0][((mbp + 1)*16 + l15) * 76 + nb * 16 + q * 4]) = pw;
    }
    *reinterpret_cast<ushort4*>(&sm.m.Ks[1][kr * 76 + kc * 4]) = k1;
  }
  __syncthreads();

  for (int t = 0; t < 64; ++t) {
    const int buf = t & 1;
    const int nt = t * 64;

    // issue global loads first: K[t+2] staging src + V[t] fragments
    ushort4 kn;
    if (t < 62)
      kn = *reinterpret_cast<const ushort4*>(
          Kb + (size_t)(nt + 128 + kr) * 32 + kc * 4);
    short8 vf[2][4];
    #pragma unroll
    for (int t2 = 0; t2 < 2; ++t2)
      #pragma unroll
      for (int ks = 0; ks < 4; ++ks)
        vf[t2][ks] = *reinterpret_cast<const short8*>(
            Vbase + (size_t)t2 * 32 * N_ + nt + ks * 16 + half * 8);

    // ---- S[t+1] into Ps[buf^1] ----
    if (t < 63) {
      short8 kf = ld8(&sm.m.Ks[buf ^ 1][(nb * 16 + l15) * 76 + q * 8]);
      float4v s0 = __builtin_amdgcn_mfma_f32_16x16x32_bf16(kf, qf0, zero4, 0, 0, 0);
      float4v s1 = __builtin_amdgcn_mfma_f32_16x16x32_bf16(kf, qf1, zero4, 0, 0, 0);
      {
        float p0 = __expf(s0.x), p1 = __expf(s0.y), p2 = __expf(s0.z), p3 = __expf(s0.w);
        rs0 += (p0 + p1) + (p2 + p3);
        uint2 pw; pw.x = pkbf(p0, p1); pw.y = pkbf(p2, p3);
        *reinterpret_cast<uint2*>(&sm.m.Ps[buf ^ 1][((mbp)*16 + l15) * 76 + nb * 16 + q * 4]) = pw;
      }
      {
        float p0 = __expf(s1.x), p1 = __expf(s1.y), p2 = __expf(s1.z), p3 = __expf(s1.w);
        rs1 += (p0 + p1) + (p2 + p3);
        uint2 pw; pw.x = pkbf(p0, p1); pw.y = pkbf(p2, p3);
        *reinterpret_cast<uint2*>(&sm.m.Ps[buf ^ 1][((mbp + 1)*16 + l15) * 76 + nb * 16 + q * 4]) = pw;
      }
      if (t < 62)
        *reinterpret_cast<ushort4*>(&sm.m.Ks[buf][kr * 76 + kc * 4]) = kn;
    }

    // ---- PV[t]: A = Ps[buf], B = vf (32x32x16) ----
    #pragma unroll
    for (int ks = 0; ks < 4; ++ks) {
      short8 pa = ld8(&sm.m.Ps[buf][(mh * 32 + l31) * 76 + ks * 16 + half * 8]);
      O[0] = __builtin_amdgcn_mfma_f32_32x32x16_bf16(pa, vf[0][ks], O[0], 0, 0, 0);
      O[1] = __builtin_amdgcn_mfma_f32_32x32x16_bf16(pa, vf[1][ks], O[1], 0, 0, 0);
    }
    __syncthreads();
  }

  // ---- row sums -> Ls, then Ls = gamma / Ls ----
  rs0 += __shfl_xor(rs0, 16); rs0 += __shfl_xor(rs0, 32);
  rs1 += __shfl_xor(rs1, 16); rs1 += __shfl_xor(rs1, 32);
  if (q == 0) {
    atomicAdd(&Ls[(mbp    ) * 16 + l15], rs0);
    atomicAdd(&Ls[(mbp + 1) * 16 + l15], rs1);
  }
  __syncthreads();
  if (tid < 64) Ls[tid] = gamma[0] / Ls[tid];
  __syncthreads();   // Ls ready; all Ps/Ks reads done -> Os may overwrite

  // ---- epilogue: D -> Os (transpose) -> coalesced stores, 2 c-chunks ----
  #pragma unroll
  for (int chunk = 0; chunk < 2; ++chunk) {
    if ((w >> 2) == chunk) {
      int cl0 = (cq & 1) * 64;
      #pragma unroll
      for (int t2 = 0; t2 < 2; ++t2) {
        int cl = cl0 + t2 * 32 + l31;
        #pragma unroll
        for (int reg = 0; reg < 16; ++reg) {
          int m = mh * 32 + (reg & 3) + 8 * (reg >> 2) + 4 * half;
          sm.Os[cl * 68 + m] = O[t2][reg] * Ls[m];
        }
      }
    }
    __syncthreads();
    {
      int cl = tid >> 2, msub = tid & 3;
      int c = chunk * 128 + cl;
      size_t idx = ((size_t)b * C_ + c) * N_ + m0 + msub * 16;
      const float* os = &sm.Os[cl * 68 + msub * 16];
      #pragma unroll
      for (int i = 0; i < 4; ++i) {
        float4 xv = *reinterpret_cast<const float4*>(x + idx + i * 4);
        float4 ov;
        ov.x = os[i * 4 + 0] + xv.x;
        ov.y = os[i * 4 + 1] + xv.y;
        ov.z = os[i * 4 + 2] + xv.z;
        ov.w = os[i * 4 + 3] + xv.w;
        *reinterpret_cast<float4*>(out + idx + i * 4) = ov;
      }
    }
    __syncthreads();
  }
}

extern "C" void kernel_launch(void* const* d_in, const int* in_sizes, int n_in,
                              void* d_out, int out_size, void* d_ws, size_t ws_size,
                              hipStream_t stream) {
  const float* x     = (const float*)d_in[0];
  const float* Wq    = (const float*)d_in[1];
  const float* bq    = (const float*)d_in[2];
  const float* Wk    = (const float*)d_in[3];
  const float* bk    = (const float*)d_in[4];
  const float* Wv    = (const float*)d_in[5];
  const float* bv    = (const float*)d_in[6];
  const float* gamma = (const float*)d_in[7];
  float* out = (float*)d_out;

  // ws: Qw bf16 2MB | Kw bf16 2MB | Vw bf16 16MB | Wc bf16 160KB | bc fp32
  uint16_t* Qw = (uint16_t*)d_ws;
  uint16_t* Kw = Qw + (size_t)B_ * N_ * 32;
  uint16_t* Vw = Kw + (size_t)B_ * N_ * 32;
  uint16_t* Wc = Vw + (size_t)B_ * C_ * N_;
  float*    bc = (float*)(Wc + 320 * 256);

  wconv_kernel<<<80, 256, 0, stream>>>(Wq, bq, Wk, bk, Wv, bv, Wc, bc);
  dim3 grid(N_ / 64, B_), block(512);
  qkv_mfma<<<grid, block, 0, stream>>>(x, Wc, bc, Qw, Kw, Vw);
  attn_mfma<<<grid, block, 0, stream>>>(Qw, Kw, Vw, x, gamma, out);
}

// Round 7
// 233.325 us; speedup vs baseline: 1.6140x; 1.6140x over previous
//
#include <hip/hip_runtime.h>
#include <stdint.h>

#define B_ 8
#define C_ 256
#define N_ 4096

typedef __attribute__((ext_vector_type(8))) short short8;
typedef __attribute__((ext_vector_type(4))) float float4v;
typedef __attribute__((ext_vector_type(16))) float floatx16;

__device__ __forceinline__ uint16_t f2bfr(float f) {
  return (uint16_t)((__float_as_uint(f) + 0x8000u) >> 16);
}
__device__ __forceinline__ uint32_t pkbf(float lo, float hi) {
  return ((__float_as_uint(hi) + 0x8000u) & 0xffff0000u) |
         ((__float_as_uint(lo) + 0x8000u) >> 16);
}
// 16B LDS read as 2x b64 (rows 152B-strided; keeps 16-bank spread of 38 dw)
__device__ __forceinline__ short8 ld8(const uint16_t* p) {
  union { ushort4 h[2]; short8 v; } u;
  u.h[0] = *reinterpret_cast<const ushort4*>(p);
  u.h[1] = *reinterpret_cast<const ushort4*>(p + 4);
  return u.v;
}

// ---------------------------------------------------------------------------
// Kernel 0: W fp32 -> Wc bf16, biases fp32.
// ---------------------------------------------------------------------------
__global__ __launch_bounds__(256) void wconv_kernel(
    const float* __restrict__ Wq, const float* __restrict__ bq,
    const float* __restrict__ Wk, const float* __restrict__ bk,
    const float* __restrict__ Wv, const float* __restrict__ bv,
    uint16_t* __restrict__ Wc, float* __restrict__ bc)
{
  int tg = blockIdx.x * 256 + threadIdx.x;
  int idx = tg * 4;
  const float* src = (idx < 8192) ? (Wq + idx)
                   : (idx < 16384) ? (Wk + (idx - 8192))
                                   : (Wv + (idx - 16384));
  float4 wv = *reinterpret_cast<const float4*>(src);
  uint2 o;
  o.x = pkbf(wv.x, wv.y);
  o.y = pkbf(wv.z, wv.w);
  *reinterpret_cast<uint2*>(Wc + idx) = o;
  if (tg < 320) bc[tg] = (tg < 32) ? bq[tg] : (tg < 64) ? bk[tg - 32] : bv[tg - 64];
}

// ---------------------------------------------------------------------------
// Kernel 1: QKV via MFMA (r5/r6 structure). V is stored PRE-SWIZZLED in MFMA
// B-frag order: block(b, tile T, cg=c>>6) of 4096 elems, inner order
// [ks=n>>4][t2=(c>>5)&1][half=(n>>3)&1][l31=c&31][j=n&7] so attn's B-frag
// loads are lane-contiguous 1KB segments (kills the V gather).
// ---------------------------------------------------------------------------
__global__ __launch_bounds__(512, 4) void qkv_mfma(
    const float* __restrict__ x, const uint16_t* __restrict__ Wc,
    const float* __restrict__ bc,
    uint16_t* __restrict__ Qw, uint16_t* __restrict__ Kw, uint16_t* __restrict__ Vw)
{
  __shared__ __align__(16) uint16_t xs[64][268];
  const int b = blockIdx.y, n0 = blockIdx.x * 64;
  const int tid = threadIdx.x;
  const int nl = tid & 63, grp = tid >> 6;
  const int w = grp, l15 = tid & 15, q = (tid & 63) >> 4;
  const int nb = w & 3;

  const float* xb = x + (size_t)b * C_ * N_ + n0;
  #pragma unroll
  for (int it = 0; it < 16; ++it) {
    int c2 = it * 16 + grp * 2;
    float f0 = xb[(size_t)c2 * N_ + nl];
    float f1 = xb[(size_t)(c2 + 1) * N_ + nl];
    *reinterpret_cast<uint32_t*>(&xs[nl][c2]) = pkbf(f0, f1);
  }
  __syncthreads();

  float4v acc[10];
  #pragma unroll
  for (int i = 0; i < 10; ++i) acc[i] = (float4v){0.f, 0.f, 0.f, 0.f};

  const int ob0 = (w >> 2) * 10;
  #pragma unroll
  for (int h2 = 0; h2 < 2; ++h2) {
    short8 bx[4];
    #pragma unroll
    for (int kb = 0; kb < 4; ++kb)
      bx[kb] = ld8(&xs[nb * 16 + l15][h2 * 128 + kb * 32 + q * 8]);
    #pragma unroll
    for (int oi = 0; oi < 10; ++oi) {
      int ob = ob0 + oi;
      const uint16_t* wr = Wc + (size_t)(ob * 16 + l15) * 256 + h2 * 128 + q * 8;
      short8 aw[4];
      #pragma unroll
      for (int kb = 0; kb < 4; ++kb)
        aw[kb] = *reinterpret_cast<const short8*>(wr + kb * 32);
      #pragma unroll
      for (int kb = 0; kb < 4; ++kb)
        acc[oi] = __builtin_amdgcn_mfma_f32_16x16x32_bf16(aw[kb], bx[kb], acc[oi], 0, 0, 0);
    }
  }

  // ---- Q/K epilogue (ob 0..3 live in waves 0-3) via LDS transpose ----
  __syncthreads();
  uint16_t (*qs)[72] = reinterpret_cast<uint16_t(*)[72]>(&xs[0][0]);
  if (w < 4) {
    #pragma unroll
    for (int oi = 0; oi < 4; ++oi) {
      float4v a = acc[oi];
      const float* bb = bc + oi * 16 + q * 4;
      uint2 pk2;
      pk2.x = pkbf(a.x + bb[0], a.y + bb[1]);
      pk2.y = pkbf(a.z + bb[2], a.w + bb[3]);
      *reinterpret_cast<uint2*>(&qs[nb * 16 + l15][oi * 16 + q * 4]) = pk2;
    }
  }
  __syncthreads();
  if (tid < 256) {
    int n = tid >> 2, sub = tid & 3;
    const uint16_t* row = qs[n];
    uint4 d0 = *reinterpret_cast<const uint4*>(&row[sub * 16]);
    uint4 d1 = *reinterpret_cast<const uint4*>(&row[sub * 16 + 8]);
    size_t nn = (size_t)b * N_ + n0 + n;
    if (sub < 2) {
      uint4* dst = reinterpret_cast<uint4*>(Qw + nn * 32 + sub * 16);
      dst[0] = d0; dst[1] = d1;
    } else {
      uint4* dst = reinterpret_cast<uint4*>(Kw + nn * 32 + (sub - 2) * 16);
      dst[0] = d0; dst[1] = d1;
    }
  }
  // ---- V epilogue into swizzled layout ----
  // n = nb*16 + l15 -> ks = nb, half = l15>>3, j = l15&7
  const size_t blk = ((size_t)b * 64 + blockIdx.x) * 4;
  const int half = l15 >> 3, j = l15 & 7;
  #pragma unroll
  for (int oi = 0; oi < 10; ++oi) {
    int ob = ob0 + oi;
    if (ob < 4) continue;
    float4v a = acc[oi];
    const float* bb = bc + ob * 16 + q * 4;
    int cb = ob * 16 - 64 + q * 4;             // 4 consecutive c share t2/cg
    size_t vaddr = (blk + (cb >> 6)) * 4096
                 + (size_t)(nb * 1024 + ((cb >> 5) & 1) * 512 + half * 256
                            + (cb & 31) * 8 + j);
    Vw[vaddr     ] = f2bfr(a.x + bb[0]);
    Vw[vaddr +  8] = f2bfr(a.y + bb[1]);
    Vw[vaddr + 16] = f2bfr(a.z + bb[2]);
    Vw[vaddr + 24] = f2bfr(a.w + bb[3]);
  }
}

// ---------------------------------------------------------------------------
// Kernel 2: MFMA flash attention, gather-free. 512 thr, grid (N/64, B).
// NO K/V LDS staging: K A-frags and swizzled-V B-frags load direct from
// global as lane-contiguous segments (L2-hot). Only P round-trips LDS
// (mandatory C->A transform), double-buffered, skewed: iter t does
// S[t+1] -> Ps[(t+1)&1] and PV[t] <- Ps[t&1], ONE barrier per iter.
// Wave w: S rows mbp=(w>>2)*2+{0,1} x keys nb=w&3; PV owns c = w*32..+31
// for BOTH m-halves (V frags shared by O[0],O[1] -> no duplication).
// ---------------------------------------------------------------------------
__global__ __launch_bounds__(512, 4) void attn_mfma(
    const uint16_t* __restrict__ Qw, const uint16_t* __restrict__ Kw,
    const uint16_t* __restrict__ Vw, const float* __restrict__ x,
    const float* __restrict__ gamma, float* __restrict__ out)
{
  __shared__ __align__(16) union Smem {
    uint16_t Ps[2][64 * 76];      // 19456 B, rows 152B (38 dw == 6 mod 32)
    float Os[128 * 69];           // 35328 B, stride 69 == 5 mod 32
  } sm;
  __shared__ float Ls[64];

  const int b = blockIdx.y, m0 = blockIdx.x * 64;
  const int tid = threadIdx.x;
  const int w = tid >> 6, lane = tid & 63;
  const int l15 = lane & 15, q = lane >> 4;
  const int l31 = lane & 31, half = lane >> 5;
  const int nb = w & 3, mbp = (w >> 2) * 2;     // S assignment
  // PV assignment: c = w*32 + l31  (cg = w>>1, t2 = w&1)

  const uint16_t* Kb = Kw + (size_t)b * N_ * 32 + (size_t)(nb * 16 + l15) * 32 + q * 8;
  const short8 qf0 = *reinterpret_cast<const short8*>(
      Qw + ((size_t)b * N_ + m0 + (mbp    ) * 16 + l15) * 32 + q * 8);
  const short8 qf1 = *reinterpret_cast<const short8*>(
      Qw + ((size_t)b * N_ + m0 + (mbp + 1) * 16 + l15) * 32 + q * 8);
  // swizzled V: lane offset within (b, tile, cg) 4096-elem block
  const uint16_t* Vb = Vw + ((size_t)b * 64 * 4 + (w >> 1)) * 4096
                     + (w & 1) * 512 + half * 256 + l31 * 8;

  floatx16 O[2];
  #pragma unroll
  for (int i = 0; i < 16; ++i) { O[0][i] = 0.f; O[1][i] = 0.f; }
  float rs0 = 0.f, rs1 = 0.f;
  const float4v zero4 = (float4v){0.f, 0.f, 0.f, 0.f};
  if (tid < 64) Ls[tid] = 0.f;

  // ---- prolog: S[0] -> Ps[0] ----
  {
    short8 kf = *reinterpret_cast<const short8*>(Kb);
    float4v s0 = __builtin_amdgcn_mfma_f32_16x16x32_bf16(kf, qf0, zero4, 0, 0, 0);
    float4v s1 = __builtin_amdgcn_mfma_f32_16x16x32_bf16(kf, qf1, zero4, 0, 0, 0);
    float p0 = __expf(s0.x), p1 = __expf(s0.y), p2 = __expf(s0.z), p3 = __expf(s0.w);
    rs0 += (p0 + p1) + (p2 + p3);
    uint2 pw; pw.x = pkbf(p0, p1); pw.y = pkbf(p2, p3);
    *reinterpret_cast<uint2*>(&sm.Ps[0][((mbp)*16 + l15) * 76 + nb * 16 + q * 4]) = pw;
    float r0 = __expf(s1.x), r1 = __expf(s1.y), r2 = __expf(s1.z), r3 = __expf(s1.w);
    rs1 += (r0 + r1) + (r2 + r3);
    uint2 rw; rw.x = pkbf(r0, r1); rw.y = pkbf(r2, r3);
    *reinterpret_cast<uint2*>(&sm.Ps[0][((mbp + 1)*16 + l15) * 76 + nb * 16 + q * 4]) = rw;
  }
  __syncthreads();

  for (int t = 0; t < 64; ++t) {
    const int buf = t & 1;

    // prefetch: K frag for tile t+1, V frags for tile t (all coalesced)
    short8 kf;
    if (t < 63)
      kf = *reinterpret_cast<const short8*>(Kb + (size_t)(t + 1) * 64 * 32);
    short8 vf[4];
    const uint16_t* vt = Vb + (size_t)t * 16384;
    #pragma unroll
    for (int ks = 0; ks < 4; ++ks)
      vf[ks] = *reinterpret_cast<const short8*>(vt + ks * 1024);

    // ---- S[t+1] -> Ps[buf^1] ----
    if (t < 63) {
      float4v s0 = __builtin_amdgcn_mfma_f32_16x16x32_bf16(kf, qf0, zero4, 0, 0, 0);
      float4v s1 = __builtin_amdgcn_mfma_f32_16x16x32_bf16(kf, qf1, zero4, 0, 0, 0);
      float p0 = __expf(s0.x), p1 = __expf(s0.y), p2 = __expf(s0.z), p3 = __expf(s0.w);
      rs0 += (p0 + p1) + (p2 + p3);
      uint2 pw; pw.x = pkbf(p0, p1); pw.y = pkbf(p2, p3);
      *reinterpret_cast<uint2*>(&sm.Ps[buf ^ 1][((mbp)*16 + l15) * 76 + nb * 16 + q * 4]) = pw;
      float r0 = __expf(s1.x), r1 = __expf(s1.y), r2 = __expf(s1.z), r3 = __expf(s1.w);
      rs1 += (r0 + r1) + (r2 + r3);
      uint2 rw; rw.x = pkbf(r0, r1); rw.y = pkbf(r2, r3);
      *reinterpret_cast<uint2*>(&sm.Ps[buf ^ 1][((mbp + 1)*16 + l15) * 76 + nb * 16 + q * 4]) = rw;
    }

    // ---- PV[t]: A = Ps[buf] (both m-halves), B = vf ----
    #pragma unroll
    for (int ks = 0; ks < 4; ++ks) {
      short8 pa0 = ld8(&sm.Ps[buf][(l31     ) * 76 + ks * 16 + half * 8]);
      short8 pa1 = ld8(&sm.Ps[buf][(32 + l31) * 76 + ks * 16 + half * 8]);
      O[0] = __builtin_amdgcn_mfma_f32_32x32x16_bf16(pa0, vf[ks], O[0], 0, 0, 0);
      O[1] = __builtin_amdgcn_mfma_f32_32x32x16_bf16(pa1, vf[ks], O[1], 0, 0, 0);
    }
    __syncthreads();
  }

  // ---- row sums -> Ls = gamma / rowsum ----
  rs0 += __shfl_xor(rs0, 16); rs0 += __shfl_xor(rs0, 32);
  rs1 += __shfl_xor(rs1, 16); rs1 += __shfl_xor(rs1, 32);
  if (q == 0) {
    atomicAdd(&Ls[(mbp    ) * 16 + l15], rs0);
    atomicAdd(&Ls[(mbp + 1) * 16 + l15], rs1);
  }
  __syncthreads();
  if (tid < 64) Ls[tid] = gamma[0] / Ls[tid];
  __syncthreads();   // Ls ready; all Ps reads done -> Os may overwrite

  // ---- epilogue: O (32x32 D layout) -> Os transpose -> coalesced stores ----
  #pragma unroll
  for (int chunk = 0; chunk < 2; ++chunk) {
    if ((w >> 2) == chunk) {
      int cl = (w & 3) * 32 + l31;
      #pragma unroll
      for (int h = 0; h < 2; ++h)
        #pragma unroll
        for (int reg = 0; reg < 16; ++reg) {
          int m = h * 32 + (reg & 3) + 8 * (reg >> 2) + 4 * half;
          sm.Os[cl * 69 + m] = O[h][reg] * Ls[m];
        }
    }
    __syncthreads();
    {
      int cl = tid >> 2, msub = tid & 3;
      int c = chunk * 128 + cl;
      size_t idx = ((size_t)b * C_ + c) * N_ + m0 + msub * 16;
      const float* os = &sm.Os[cl * 69 + msub * 16];
      #pragma unroll
      for (int i = 0; i < 4; ++i) {
        float4 xv = *reinterpret_cast<const float4*>(x + idx + i * 4);
        float4 ov;
        ov.x = os[i * 4 + 0] + xv.x;
        ov.y = os[i * 4 + 1] + xv.y;
        ov.z = os[i * 4 + 2] + xv.z;
        ov.w = os[i * 4 + 3] + xv.w;
        *reinterpret_cast<float4*>(out + idx + i * 4) = ov;
      }
    }
    __syncthreads();
  }
}

extern "C" void kernel_launch(void* const* d_in, const int* in_sizes, int n_in,
                              void* d_out, int out_size, void* d_ws, size_t ws_size,
                              hipStream_t stream) {
  const float* x     = (const float*)d_in[0];
  const float* Wq    = (const float*)d_in[1];
  const float* bq    = (const float*)d_in[2];
  const float* Wk    = (const float*)d_in[3];
  const float* bk    = (const float*)d_in[4];
  const float* Wv    = (const float*)d_in[5];
  const float* bv    = (const float*)d_in[6];
  const float* gamma = (const float*)d_in[7];
  float* out = (float*)d_out;

  // ws: Qw bf16 2MB | Kw bf16 2MB | Vw bf16 16MB (swizzled) | Wc | bc
  uint16_t* Qw = (uint16_t*)d_ws;
  uint16_t* Kw = Qw + (size_t)B_ * N_ * 32;
  uint16_t* Vw = Kw + (size_t)B_ * N_ * 32;
  uint16_t* Wc = Vw + (size_t)B_ * C_ * N_;
  float*    bc = (float*)(Wc + 320 * 256);

  wconv_kernel<<<80, 256, 0, stream>>>(Wq, bq, Wk, bk, Wv, bv, Wc, bc);
  dim3 grid(N_ / 64, B_), block(512);
  qkv_mfma<<<grid, block, 0, stream>>>(x, Wc, bc, Qw, Kw, Vw);
  attn_mfma<<<grid, block, 0, stream>>>(Qw, Kw, Vw, x, gamma, out);
}